// Round 4
// baseline (283.391 us; speedup 1.0000x reference)
//
#include <hip/hip_runtime.h>
#include <hip/hip_bf16.h>

typedef __attribute__((ext_vector_type(8))) short s16x8;
typedef __attribute__((ext_vector_type(4))) float f32x4;

__device__ __forceinline__ unsigned short f2bfu(float x) {
  __hip_bfloat16 b = __float2bfloat16(x);
  return *reinterpret_cast<unsigned short*>(&b);
}
__device__ __forceinline__ short f2bfs(float x) { return (short)f2bfu(x); }

// ---------------- transpose + downcast: dst[C][R] = bf16(src[R][C]) ----------
__global__ __launch_bounds__(256) void transpose_k(const float* __restrict__ src,
                                                   unsigned short* __restrict__ dst,
                                                   int R, int C) {
  __shared__ float t[32][33];
  const int c0 = blockIdx.x * 32, r0 = blockIdx.y * 32;
  const int tx = threadIdx.x & 31, ty = threadIdx.x >> 5;
#pragma unroll
  for (int i = 0; i < 32; i += 8)
    t[ty + i][tx] = src[(size_t)(r0 + ty + i) * C + (c0 + tx)];
  __syncthreads();
#pragma unroll
  for (int i = 0; i < 32; i += 8)
    dst[(size_t)(c0 + ty + i) * R + (r0 + tx)] = f2bfu(t[tx][ty + i]);
}

// ---------------- per-batch precompute (512 threads) ----------------
// blocks 0..255: batch b -> w[256], P[1024], R[1024]; block 256: C[k]
__global__ __launch_bounds__(512) void precompute_k(
    const float* __restrict__ X0, const float* __restrict__ Xs,
    const float* __restrict__ Wq, const float* __restrict__ bq,
    const float* __restrict__ Wk, const float* __restrict__ bk,
    const float* __restrict__ Wv, const float* __restrict__ bv,
    const float* __restrict__ gp, const float* __restrict__ W1,
    const float* __restrict__ b1,
    float* __restrict__ Cws, float* __restrict__ Wws,
    float* __restrict__ Pws, float* __restrict__ Rws) {
  const int t = threadIdx.x;
  const int blk = blockIdx.x;
  __shared__ float x0f[512];
  __shared__ float v0f[512];
  __shared__ float sv[256];
  __shared__ float q0[64], k0s[64];
  __shared__ float scal[4];

  if (blk == 256) {
    const float g = gp[0];
    x0f[t] = bv[t];
    __syncthreads();
    float a0 = 0, a1 = 0;
    for (int d = 0; d < 512; ++d) {
      const float2 w = *reinterpret_cast<const float2*>(&W1[d * 1024 + 2 * t]);
      const float x = x0f[d];
      a0 = fmaf(x, w.x, a0);
      a1 = fmaf(x, w.y, a1);
    }
    Cws[2 * t + 0] = fmaf(g, a0, b1[2 * t + 0]);
    Cws[2 * t + 1] = fmaf(g, a1, b1[2 * t + 1]);
    return;
  }
  const int b = blk;
  x0f[t] = X0[b * 512 + t];
  if (t < 256) sv[t] = (t == 0) ? 1.0f : Xs[b * 255 + t - 1];
  __syncthreads();
  if (t < 128) {  // q0 / k0
    const float* W = (t < 64) ? Wq : Wk;
    const int j = t & 63;
    float a = 0;
    for (int d = 0; d < 512; ++d) a = fmaf(x0f[d], W[d * 64 + j], a);
    if (t < 64) q0[j] = a; else k0s[j] = a;
  }
  {  // v0 = x0 @ Wv : one column per thread
    float a = 0;
    for (int d = 0; d < 512; ++d) a = fmaf(x0f[d], Wv[d * 512 + t], a);
    v0f[t] = a;
  }
  __syncthreads();
  if (t == 0) {
    float al = 0, g2 = 0;
    for (int j = 0; j < 64; ++j) {
      al = fmaf(q0[j], k0s[j], al);
      g2 = fmaf(bq[j], k0s[j], g2);
    }
    float mx = sv[0], mn = sv[0];
    for (int m = 1; m < 256; ++m) { mx = fmaxf(mx, sv[m]); mn = fminf(mn, sv[m]); }
    scal[0] = al; scal[1] = g2; scal[2] = mx; scal[3] = mn;
  }
  __syncthreads();
  if (t < 256) {  // w_n
    const float c = fmaf(scal[0], sv[t], scal[1]);
    const float M = (c >= 0.f) ? c * scal[2] : c * scal[3];
    float Z = 0, Wm = 0;
    for (int m = 0; m < 256; ++m) {
      const float e = __expf(fmaf(c, sv[m], -M));
      Z += e;
      Wm = fmaf(sv[m], e, Wm);
    }
    Wws[b * 256 + t] = Wm / Z;
  }
  {  // P = v0@W1, R = x0@W1 : two columns per thread
    float p0 = 0, p1 = 0, r0 = 0, r1 = 0;
    for (int d = 0; d < 512; ++d) {
      const float2 w = *reinterpret_cast<const float2*>(&W1[d * 1024 + 2 * t]);
      const float xv = x0f[d], vv = v0f[d];
      p0 = fmaf(vv, w.x, p0); p1 = fmaf(vv, w.y, p1);
      r0 = fmaf(xv, w.x, r0); r1 = fmaf(xv, w.y, r1);
    }
    float* Pp = Pws + b * 1024 + 2 * t;
    float* Rp = Rws + b * 1024 + 2 * t;
    Pp[0] = p0; Pp[1] = p1;
    Rp[0] = r0; Rp[1] = r1;
  }
}

// ---------------- fused GEMM: out = relu(relu(h1@W2+b2)@W3 + b3) -------------
// BM=128, BN=512, BK=32, 512 thr (8 waves 2x4), wave tile 64x128.
// A-fragments generated IN REGISTERS from the rank-2 form (no A LDS).
// B (W2T) staged via global_load_lds into [ks][row][8] layout, dbuf 2x32KB.
// Phase B: h2t row-halves (64x512 bf16 = 64KB, reusing the same LDS),
//          W3T fragments loaded straight from global (L2-resident).
__global__ __launch_bounds__(512) void fused_k(
    const float* __restrict__ Xs, const float* __restrict__ gp,
    const unsigned short* __restrict__ W2T,  // [512][1024] bf16
    const float* __restrict__ b2,
    const unsigned short* __restrict__ W3T,  // [128][512] bf16
    const float* __restrict__ b3,
    const float* __restrict__ Cws, const float* __restrict__ Wws,
    const float* __restrict__ Pws, const float* __restrict__ Rws,
    float* __restrict__ out)  // [65536][128] f32
{
  __shared__ __align__(16) unsigned short smem[32768];  // 64 KB
  const int tid = threadIdx.x;
  const int lane = tid & 63;
  const int wid = tid >> 6;
  const int wr = wid >> 2, wc = wid & 3;
  const int la = lane & 15, q4 = lane >> 4;
  const int rq = q4 * 4;
  const int m0 = blockIdx.x * 128;
  const int b = m0 >> 8;
  const float g = gp[0];

  // per-m-tile row scalars (row = la within each 16-row fragment)
  float gwm[4], srm[4];
#pragma unroll
  for (int m = 0; m < 4; ++m) {
    const int tok = (m0 & 255) + wr * 64 + m * 16 + la;
    gwm[m] = g * Wws[b * 256 + tok];
    srm[m] = (tok == 0) ? 1.0f : Xs[b * 255 + tok - 1];
  }
  const float* Pp = Pws + b * 1024 + q4 * 8;
  const float* Rp = Rws + b * 1024 + q4 * 8;
  const float* Cp = Cws + q4 * 8;

  // B-staging: 4 DMA chunks per wave; chunk = wid*4+ii -> ks = chunk>>3,
  // r0 = (chunk&7)*64. LDS dest is wave-uniform; lane fills row r0+lane.
  auto stage = [&](int buf, int k0) {
#pragma unroll
    for (int ii = 0; ii < 4; ++ii) {
      const int chunk = wid * 4 + ii;
      const int ks = chunk >> 3, r0 = (chunk & 7) * 64;
      const unsigned short* src = W2T + (size_t)(r0 + lane) * 1024 + k0 + ks * 8;
      __builtin_amdgcn_global_load_lds(
          (const __attribute__((address_space(1))) void*)src,
          (__attribute__((address_space(3))) void*)&smem[buf * 16384 + ks * 4096 + r0 * 8],
          16, 0, 0);
    }
  };

  f32x4 acc[4][8];
#pragma unroll
  for (int m = 0; m < 4; ++m)
#pragma unroll
    for (int nf = 0; nf < 8; ++nf) acc[m][nf] = (f32x4){0.f, 0.f, 0.f, 0.f};

  stage(0, 0);
  __syncthreads();

  for (int step = 0; step < 32; ++step) {
    const int cur = step & 1;
    if (step + 1 < 32) stage(cur ^ 1, (step + 1) * 32);
    // generate A fragments in registers from rank-2 form
    const int k0 = step * 32;
    const float4 P0 = *reinterpret_cast<const float4*>(Pp + k0);
    const float4 P1 = *reinterpret_cast<const float4*>(Pp + k0 + 4);
    const float4 R0 = *reinterpret_cast<const float4*>(Rp + k0);
    const float4 R1 = *reinterpret_cast<const float4*>(Rp + k0 + 4);
    const float4 C0 = *reinterpret_cast<const float4*>(Cp + k0);
    const float4 C1 = *reinterpret_cast<const float4*>(Cp + k0 + 4);
    s16x8 af[4];
#pragma unroll
    for (int m = 0; m < 4; ++m) {
      const float gw = gwm[m], sr = srm[m];
      s16x8 v;
      v[0] = f2bfs(fmaxf(fmaf(gw, P0.x, fmaf(sr, R0.x, C0.x)), 0.f));
      v[1] = f2bfs(fmaxf(fmaf(gw, P0.y, fmaf(sr, R0.y, C0.y)), 0.f));
      v[2] = f2bfs(fmaxf(fmaf(gw, P0.z, fmaf(sr, R0.z, C0.z)), 0.f));
      v[3] = f2bfs(fmaxf(fmaf(gw, P0.w, fmaf(sr, R0.w, C0.w)), 0.f));
      v[4] = f2bfs(fmaxf(fmaf(gw, P1.x, fmaf(sr, R1.x, C1.x)), 0.f));
      v[5] = f2bfs(fmaxf(fmaf(gw, P1.y, fmaf(sr, R1.y, C1.y)), 0.f));
      v[6] = f2bfs(fmaxf(fmaf(gw, P1.z, fmaf(sr, R1.z, C1.z)), 0.f));
      v[7] = f2bfs(fmaxf(fmaf(gw, P1.w, fmaf(sr, R1.w, C1.w)), 0.f));
      af[m] = v;
    }
#pragma unroll
    for (int nf = 0; nf < 8; ++nf) {
      const s16x8 bfr = *reinterpret_cast<const s16x8*>(
          &smem[cur * 16384 + q4 * 4096 + (wc * 128 + nf * 16 + la) * 8]);
#pragma unroll
      for (int m = 0; m < 4; ++m)
        acc[m][nf] = __builtin_amdgcn_mfma_f32_16x16x32_bf16(af[m], bfr, acc[m][nf], 0, 0, 0);
    }
    __syncthreads();
  }

  // ---- phase B: two row-halves; h2t = [j2 0..63][64 rows][8] (64 KB) ----
  for (int h = 0; h < 2; ++h) {
    if (wr == h) {
#pragma unroll
      for (int nf = 0; nf < 8; ++nf) {
        const int col = wc * 128 + nf * 16 + la;  // = k index of phase B
        const float bb = b2[col];
        const int jbase = (col >> 3) * 512 + (col & 7);
#pragma unroll
        for (int m = 0; m < 4; ++m) {
          const int lr = m * 16 + rq;
#pragma unroll
          for (int qq = 0; qq < 4; ++qq)
            smem[jbase + (lr + qq) * 8] = f2bfu(fmaxf(acc[m][nf][qq] + bb, 0.f));
        }
      }
    }
    __syncthreads();
    // out rows [h*64, h*64+64): 8 waves 2x4, wave tile 32 rows x 32 cols
    f32x4 acc2[2][2];
#pragma unroll
    for (int mi = 0; mi < 2; ++mi)
#pragma unroll
      for (int ni = 0; ni < 2; ++ni) acc2[mi][ni] = (f32x4){0.f, 0.f, 0.f, 0.f};
    for (int kstep = 0; kstep < 16; ++kstep) {
      s16x8 af2[2], bf2[2];
#pragma unroll
      for (int mi = 0; mi < 2; ++mi)
        af2[mi] = *reinterpret_cast<const s16x8*>(
            &smem[(kstep * 4 + q4) * 512 + (wr * 32 + mi * 16 + la) * 8]);
#pragma unroll
      for (int ni = 0; ni < 2; ++ni)
        bf2[ni] = *reinterpret_cast<const s16x8*>(
            W3T + (size_t)(wc * 32 + ni * 16 + la) * 512 + kstep * 32 + q4 * 8);
#pragma unroll
      for (int mi = 0; mi < 2; ++mi)
#pragma unroll
        for (int ni = 0; ni < 2; ++ni)
          acc2[mi][ni] = __builtin_amdgcn_mfma_f32_16x16x32_bf16(af2[mi], bf2[ni], acc2[mi][ni], 0, 0, 0);
    }
#pragma unroll
    for (int ni = 0; ni < 2; ++ni) {
      const int col = wc * 32 + ni * 16 + la;
      const float bb = b3[col];
#pragma unroll
      for (int mi = 0; mi < 2; ++mi) {
        const int row = m0 + h * 64 + wr * 32 + mi * 16 + rq;
#pragma unroll
        for (int qq = 0; qq < 4; ++qq)
          out[(size_t)(row + qq) * 128 + col] = fmaxf(acc2[mi][ni][qq] + bb, 0.f);
      }
    }
    __syncthreads();
  }
}

extern "C" void kernel_launch(void* const* d_in, const int* in_sizes, int n_in,
                              void* d_out, int out_size, void* d_ws, size_t ws_size,
                              hipStream_t stream) {
  const float* X0 = (const float*)d_in[0];
  const float* Xs = (const float*)d_in[1];
  const float* Wq = (const float*)d_in[2];
  const float* bq = (const float*)d_in[3];
  const float* Wk = (const float*)d_in[4];
  const float* bk = (const float*)d_in[5];
  const float* Wv = (const float*)d_in[6];
  const float* bv = (const float*)d_in[7];
  const float* gp = (const float*)d_in[8];
  const float* W1 = (const float*)d_in[9];
  const float* b1 = (const float*)d_in[10];
  const float* W2 = (const float*)d_in[11];
  const float* b2 = (const float*)d_in[12];
  const float* W3 = (const float*)d_in[13];
  const float* b3 = (const float*)d_in[14];

  char* ws = (char*)d_ws;
  float* Cws = (float*)(ws);                              //   4 KB
  float* Wws = (float*)(ws + 4096);                       // 256 KB
  float* Pws = (float*)(ws + 266240);                     //   1 MB
  float* Rws = (float*)(ws + 1314816);                    //   1 MB
  unsigned short* W2T = (unsigned short*)(ws + 2363392);  //   1 MB (bf16)
  unsigned short* W3T = (unsigned short*)(ws + 3411968);  // 128 KB (bf16)
  float* out = (float*)d_out;

  hipLaunchKernelGGL(transpose_k, dim3(16, 32), dim3(256), 0, stream, W2, W2T, 1024, 512);
  hipLaunchKernelGGL(transpose_k, dim3(4, 16), dim3(256), 0, stream, W3, W3T, 512, 128);
  hipLaunchKernelGGL(precompute_k, dim3(257), dim3(512), 0, stream,
                     X0, Xs, Wq, bq, Wk, bk, Wv, bv, gp, W1, b1, Cws, Wws, Pws, Rws);
  hipLaunchKernelGGL(fused_k, dim3(512), dim3(512), 0, stream,
                     Xs, gp, W2T, b2, W3T, b3, Cws, Wws, Pws, Rws, out);
}